// Round 2
// baseline (98.210 us; speedup 1.0000x reference)
//
#include <hip/hip_runtime.h>

typedef _Float16 half8 __attribute__((ext_vector_type(8)));
typedef float f32x4  __attribute__((ext_vector_type(4)));

#define DEVI __device__ __forceinline__

// problem constants (B,H,W,C fixed by the reference)
constexpr int Bc = 8;
constexpr int Hc = 224;
constexpr int Wc = 224;
constexpr int Cc = 256;
constexpr int NQ = 64;
constexpr int TS = 32;        // cell tile side (224/7)
constexpr int Lc = TS * TS;   // 1024 positions per cell
constexpr int KL = 64;        // l-chunk
constexpr int NT = Lc / KL;   // 16 chunks

// fp16-element index inside a 64x256 chunk, subtiled [l/4][c/16][4][16]
// (c-contiguous runs of 16 -> serves b128 reads for QK^T A-frags; the same
//  layout serves ds_read_b64_tr_b16 for PV B-frags in a later round)
DEVI int subidx(int l, int c) {
  return ((((l >> 2) << 4) | (c >> 4)) << 6) | (((l & 3) << 4) | (c & 15));
}

union H2U { _Float16 h[2]; uint u; };

__global__ __launch_bounds__(256, 2) void attn_cells(
    const float* __restrict__ img,   // fp32 [B,224,224,256]
    const float* __restrict__ qry,   // fp32 [64,256]
    float* __restrict__ out)         // fp32 [B,49,64,256]
{
  __shared__ _Float16 Rlds[2][KL * Cc]; // 2 x 32KB, subtiled fp16
  __shared__ _Float16 Plds[4][16 * KL]; // per-wave P rows (fp16), swizzled
  __shared__ float    Slds[NQ];         // per-chunk rescale factors
  __shared__ float    Llds[NQ];         // final sum-exp

  const int tid  = threadIdx.x;
  const int w    = tid >> 6;          // wave 0..3
  const int lane = tid & 63;
  const int lp   = lane & 15;
  const int gq   = lane >> 4;         // 0..3

  const int bn = blockIdx.x;          // cell id: b*49 + (i*7+j)
  const int b  = bn / 49;
  const int n  = bn % 49;
  const int i0 = n / 7, j0 = n % 7;

  const long cellbase = (((long)b * Hc + i0 * TS) * Wc + j0 * TS) * Cc;

  // staging decode: 8 granules of 8 elements per thread; granule G covers
  // chunk elements [8G, 8G+8) == R[l][c..c+7] in the subtiled layout
  int goff[8], lds_off[8];
  #pragma unroll
  for (int s = 0; s < 8; ++s) {
    int G   = s * 256 + tid;                       // 0..2047
    int blk = G >> 3, sub = G & 7;
    int l   = ((blk >> 4) << 2) | ((sub >> 1) & 3);
    int c   = ((blk & 15) << 4) | ((sub & 1) << 3);
    int y   = l >> 5, x = l & 31;
    goff[s]    = (y * Wc + x) * Cc + c;            // + t*2*Wc*Cc per chunk
    lds_off[s] = G << 3;                           // fp16 elements
  }

  // Q fragments (B-operand of S^T = R.Q^T): lane holds Q[16w+lp][32kc+8gq+j]
  half8 bq[8];
  {
    const int qrow = (w << 4) | lp;
    #pragma unroll
    for (int kc = 0; kc < 8; ++kc) {
      const float* qp = &qry[qrow * Cc + kc * 32 + gq * 8];
      f32x4 lo = *(const f32x4*)qp;
      f32x4 hi = *(const f32x4*)(qp + 4);
      half8 h;
      #pragma unroll
      for (int j = 0; j < 4; ++j) { h[j] = (_Float16)lo[j]; h[j + 4] = (_Float16)hi[j]; }
      bq[kc] = h;
    }
  }

  f32x4 acc[4][4];
  #pragma unroll
  for (int qb = 0; qb < 4; ++qb)
    #pragma unroll
    for (int cb = 0; cb < 4; ++cb) acc[qb][cb] = f32x4{0.f, 0.f, 0.f, 0.f};

  float mrun = -3.0e38f;
  float lsum = 0.0f;

  // prologue: stage chunk 0 (fp32 -> fp16 convert)
  {
    const float* gb = img + cellbase;
    #pragma unroll
    for (int s = 0; s < 8; ++s) {
      f32x4 lo = *(const f32x4*)&gb[goff[s]];
      f32x4 hi = *(const f32x4*)&gb[goff[s] + 4];
      half8 h;
      #pragma unroll
      for (int j = 0; j < 4; ++j) { h[j] = (_Float16)lo[j]; h[j + 4] = (_Float16)hi[j]; }
      *(half8*)&Rlds[0][lds_off[s]] = h;
    }
  }
  __syncthreads();

  for (int t = 0; t < NT; ++t) {
    const int pb = t & 1;
    const _Float16* Rbuf = &Rlds[pb][0];

    if (t + 1 < NT) {   // stage next chunk into the free buffer
      const float* gb = img + cellbase + (long)(t + 1) * (2 * Wc * Cc);
      _Float16* Rn = &Rlds[pb ^ 1][0];
      #pragma unroll
      for (int s = 0; s < 8; ++s) {
        f32x4 lo = *(const f32x4*)&gb[goff[s]];
        f32x4 hi = *(const f32x4*)&gb[goff[s] + 4];
        half8 h;
        #pragma unroll
        for (int j = 0; j < 4; ++j) { h[j] = (_Float16)lo[j]; h[j + 4] = (_Float16)hi[j]; }
        *(half8*)&Rn[lds_off[s]] = h;
      }
    }

    // ---- S^T = R . Q^T  (wave handles q rows 16w..16w+15) ----
    f32x4 sv[4];
    #pragma unroll
    for (int lb = 0; lb < 4; ++lb) sv[lb] = f32x4{0.f, 0.f, 0.f, 0.f};
    #pragma unroll
    for (int kc = 0; kc < 8; ++kc) {
      #pragma unroll
      for (int lb = 0; lb < 4; ++lb) {
        half8 a = *(const half8*)&Rbuf[subidx(lb * 16 + lp, kc * 32 + gq * 8)];
        sv[lb] = __builtin_amdgcn_mfma_f32_16x16x32_f16(a, bq[kc], sv[lb], 0, 0, 0);
      }
    }
    // lane holds S^T[l = 16lb+4gq+r][q = 16w+lp]

    // ---- online softmax for q = 16w+lp ----
    float cmax = sv[0][0];
    #pragma unroll
    for (int lb = 0; lb < 4; ++lb)
      #pragma unroll
      for (int r = 0; r < 4; ++r) cmax = fmaxf(cmax, sv[lb][r]);
    cmax = fmaxf(cmax, __shfl_xor(cmax, 16));
    cmax = fmaxf(cmax, __shfl_xor(cmax, 32));

    float mnew  = fmaxf(mrun, cmax);
    float scale = __expf(mrun - mnew);

    float ps = 0.0f;
    float pv[4][4];
    #pragma unroll
    for (int lb = 0; lb < 4; ++lb)
      #pragma unroll
      for (int r = 0; r < 4; ++r) {
        float p = __expf(sv[lb][r] - mnew);
        pv[lb][r] = p; ps += p;
      }
    ps += __shfl_xor(ps, 16);
    ps += __shfl_xor(ps, 32);
    lsum = lsum * scale + ps;
    mrun = mnew;

    // write P rows (fp16) to per-wave swizzled LDS: byte (lp*128 + 2l) ^ ((lp&7)<<4)
    {
      char* Pw = (char*)&Plds[w][0];
      #pragma unroll
      for (int lb = 0; lb < 4; ++lb) {
        H2U lo, hi;
        lo.h[0] = (_Float16)pv[lb][0]; lo.h[1] = (_Float16)pv[lb][1];
        hi.h[0] = (_Float16)pv[lb][2]; hi.h[1] = (_Float16)pv[lb][3];
        int base = lp * 128 + lb * 32 + gq * 8;   // l = 16lb + 4gq
        int swz  = (lp & 7) << 4;
        *(uint*)(Pw + ((base ^ swz)))     = lo.u;
        *(uint*)(Pw + ((base ^ swz) + 4)) = hi.u;
      }
      if (lane < 16) Slds[w * 16 + lp] = scale;
    }

    __syncthreads();   // P + scale visible to all waves

    // ---- PV: wave computes O[all 64 q][c slice 64w..64w+64) ----
    #pragma unroll
    for (int qb = 0; qb < 4; ++qb) {
      f32x4 sc = *(const f32x4*)&Slds[qb * 16 + gq * 4];
      #pragma unroll
      for (int cb = 0; cb < 4; ++cb) acc[qb][cb] *= sc;
    }

    #pragma unroll
    for (int kc = 0; kc < 2; ++kc) {
      half8 pa[4];
      #pragma unroll
      for (int qb = 0; qb < 4; ++qb) {
        const char* Pr = (const char*)&Plds[qb][0];
        int off = (lp * 128 + gq * 16 + kc * 64) ^ ((lp & 7) << 4);
        pa[qb] = *(const half8*)(Pr + off);
      }
      half8 pbf[4];
      #pragma unroll
      for (int cb = 0; cb < 4; ++cb) {
        const int c  = w * 64 + cb * 16 + lp;
        const int l0 = kc * 32 + gq * 8;
        half8 v;
        #pragma unroll
        for (int j = 0; j < 8; ++j) v[j] = Rbuf[subidx(l0 + j, c)];
        pbf[cb] = v;
      }
      #pragma unroll
      for (int qb = 0; qb < 4; ++qb)
        #pragma unroll
        for (int cb = 0; cb < 4; ++cb)
          acc[qb][cb] = __builtin_amdgcn_mfma_f32_16x16x32_f16(pa[qb], pbf[cb], acc[qb][cb], 0, 0, 0);
    }

    __syncthreads();   // frees R buffer (for stage t+2) and P region
  }

  // ---- epilogue: divide by sum-exp, write fp32 ----
  if (lane < 16) Llds[w * 16 + lp] = lsum;
  __syncthreads();

  float* ob = out + (long)bn * NQ * Cc;
  #pragma unroll
  for (int qb = 0; qb < 4; ++qb) {
    f32x4 lv = *(const f32x4*)&Llds[qb * 16 + gq * 4];
    #pragma unroll
    for (int r = 0; r < 4; ++r) {
      const float iv = 1.0f / lv[r];
      const int q = qb * 16 + gq * 4 + r;
      #pragma unroll
      for (int cb = 0; cb < 4; ++cb) {
        const int c = w * 64 + cb * 16 + lp;
        ob[q * Cc + c] = acc[qb][cb][r] * iv;
      }
    }
  }
}

extern "C" void kernel_launch(void* const* d_in, const int* in_sizes, int n_in,
                              void* d_out, int out_size, void* d_ws, size_t ws_size,
                              hipStream_t stream) {
  const float* img = (const float*)d_in[0];
  const float* qry = (const float*)d_in[1];
  float* outp      = (float*)d_out;
  dim3 grid(Bc * 49), block(256);
  attn_cells<<<grid, block, 0, stream>>>(img, qry, outp);
}

// Round 3
// 95.293 us; speedup vs baseline: 1.0306x; 1.0306x over previous
//
#include <hip/hip_runtime.h>

typedef _Float16 half8 __attribute__((ext_vector_type(8)));
typedef _Float16 half4 __attribute__((ext_vector_type(4)));
typedef float f32x4  __attribute__((ext_vector_type(4)));

#define DEVI __device__ __forceinline__

// problem constants (B,H,W,C fixed by the reference)
constexpr int Bc = 8;
constexpr int Hc = 224;
constexpr int Wc = 224;
constexpr int Cc = 256;
constexpr int NQ = 64;
constexpr int TS = 32;        // cell tile side (224/7)
constexpr int Lc = TS * TS;   // 1024 positions per cell
constexpr int KL = 64;        // l-chunk
constexpr int NT = Lc / KL;   // 16 chunks

// fp16-element index inside a 64x256 chunk, subtiled [l/4][c/16][4][16]
// (c-contiguous 16-runs -> b128 reads for QK^T A-frags; 4x16 subtiles ->
//  ds_read_b64_tr_b16 for PV B-frags)
DEVI int subidx(int l, int c) {
  return ((((l >> 2) << 4) | (c >> 4)) << 6) | (((l & 3) << 4) | (c & 15));
}

// LDS byte offset of a shared-memory pointer (generic -> AS(3) addrspacecast)
DEVI uint ldsoff(const void* p) {
  return (uint)(uintptr_t)(const __attribute__((address_space(3))) char*)p;
}

union H2U { _Float16 h[2]; uint u; };

__global__ __launch_bounds__(256, 2) void attn_cells(
    const float* __restrict__ img,   // fp32 [B,224,224,256]
    const float* __restrict__ qry,   // fp32 [64,256]
    float* __restrict__ out)         // fp32 [B,49,64,256]
{
  __shared__ _Float16 Rlds[2][KL * Cc]; // 2 x 32KB, subtiled fp16
  __shared__ _Float16 Plds[4][16 * KL]; // per-wave P rows (fp16), swizzled
  __shared__ float    Slds[NQ];         // per-chunk rescale factors
  __shared__ float    Llds[NQ];         // final sum-exp

  const int tid  = threadIdx.x;
  const int w    = tid >> 6;          // wave 0..3
  const int lane = tid & 63;
  const int lp   = lane & 15;
  const int gq   = lane >> 4;         // 0..3

  const int bn = blockIdx.x;          // cell id: b*49 + (i*7+j)
  const int b  = bn / 49;
  const int n  = bn % 49;
  const int i0 = n / 7, j0 = n % 7;

  const long cellbase = (((long)b * Hc + i0 * TS) * Wc + j0 * TS) * Cc;

  // staging decode: 8 granules of 8 elements per thread; granule G covers
  // chunk elements [8G, 8G+8) == R[l][c..c+7] in the subtiled layout
  int goff[8], lds_off[8];
  #pragma unroll
  for (int s = 0; s < 8; ++s) {
    int G   = s * 256 + tid;                       // 0..2047
    int blk = G >> 3, sub = G & 7;
    int l   = ((blk >> 4) << 2) | ((sub >> 1) & 3);
    int c   = ((blk & 15) << 4) | ((sub & 1) << 3);
    int y   = l >> 5, x = l & 31;
    goff[s]    = (y * Wc + x) * Cc + c;            // + t*2*Wc*Cc per chunk
    lds_off[s] = G << 3;                           // fp16 elements
  }

  // Q fragments (B-operand of S^T = R.Q^T): lane holds Q[16w+lp][32kc+8gq+j]
  half8 bq[8];
  {
    const int qrow = (w << 4) | lp;
    #pragma unroll
    for (int kc = 0; kc < 8; ++kc) {
      const float* qp = &qry[qrow * Cc + kc * 32 + gq * 8];
      f32x4 lo = *(const f32x4*)qp;
      f32x4 hi = *(const f32x4*)(qp + 4);
      half8 h;
      #pragma unroll
      for (int j = 0; j < 4; ++j) { h[j] = (_Float16)lo[j]; h[j + 4] = (_Float16)hi[j]; }
      bq[kc] = h;
    }
  }

  f32x4 acc[4][4];
  #pragma unroll
  for (int qb = 0; qb < 4; ++qb)
    #pragma unroll
    for (int cb = 0; cb < 4; ++cb) acc[qb][cb] = f32x4{0.f, 0.f, 0.f, 0.f};

  float mrun = -3.0e38f;
  float lsum = 0.0f;

  // prologue: stage chunk 0 (fp32 -> fp16 convert)
  {
    const float* gb = img + cellbase;
    #pragma unroll
    for (int s = 0; s < 8; ++s) {
      f32x4 lo = *(const f32x4*)&gb[goff[s]];
      f32x4 hi = *(const f32x4*)&gb[goff[s] + 4];
      half8 h;
      #pragma unroll
      for (int j = 0; j < 4; ++j) { h[j] = (_Float16)lo[j]; h[j + 4] = (_Float16)hi[j]; }
      *(half8*)&Rlds[0][lds_off[s]] = h;
    }
  }
  __syncthreads();

  // per-lane base for PV tr-reads: lane (gq,lp) reads 4 contiguous fp16 at
  // R[l0 + (lp>>2)][c0 + 4*(lp&3)]; the HW cross-lane permutation then
  // delivers out[j] = R[l0+j][c0+lp].  l0 = kc*32+gq*8+u*4, c0 = w*64+cb*16.
  // elem = (kc*8+gq*2+u)*1024 + (w*4+cb)*64 + (lp>>2)*16 + (lp&3)*4
  const uint trlane = (uint)(gq * 4096 + w * 512 +
                             ((((lp >> 2) << 4) | ((lp & 3) << 2)) << 1));

  for (int t = 0; t < NT; ++t) {
    const int pb = t & 1;
    const _Float16* Rbuf = &Rlds[pb][0];
    const uint trbase = ldsoff(Rbuf) + trlane;

    if (t + 1 < NT) {   // stage next chunk into the free buffer
      const float* gb = img + cellbase + (long)(t + 1) * (2 * Wc * Cc);
      _Float16* Rn = &Rlds[pb ^ 1][0];
      #pragma unroll
      for (int s = 0; s < 8; ++s) {
        f32x4 lo = *(const f32x4*)&gb[goff[s]];
        f32x4 hi = *(const f32x4*)&gb[goff[s] + 4];
        half8 h;
        #pragma unroll
        for (int j = 0; j < 4; ++j) { h[j] = (_Float16)lo[j]; h[j + 4] = (_Float16)hi[j]; }
        *(half8*)&Rn[lds_off[s]] = h;
      }
    }

    // ---- S^T = R . Q^T  (wave handles q rows 16w..16w+15) ----
    f32x4 sv[4];
    #pragma unroll
    for (int lb = 0; lb < 4; ++lb) sv[lb] = f32x4{0.f, 0.f, 0.f, 0.f};
    #pragma unroll
    for (int kc = 0; kc < 8; ++kc) {
      #pragma unroll
      for (int lb = 0; lb < 4; ++lb) {
        half8 a = *(const half8*)&Rbuf[subidx(lb * 16 + lp, kc * 32 + gq * 8)];
        sv[lb] = __builtin_amdgcn_mfma_f32_16x16x32_f16(a, bq[kc], sv[lb], 0, 0, 0);
      }
    }
    // lane holds S^T[l = 16lb+4gq+r][q = 16w+lp]

    // ---- online softmax for q = 16w+lp ----
    float cmax = sv[0][0];
    #pragma unroll
    for (int lb = 0; lb < 4; ++lb)
      #pragma unroll
      for (int r = 0; r < 4; ++r) cmax = fmaxf(cmax, sv[lb][r]);
    cmax = fmaxf(cmax, __shfl_xor(cmax, 16));
    cmax = fmaxf(cmax, __shfl_xor(cmax, 32));

    float mnew  = fmaxf(mrun, cmax);
    float scale = __expf(mrun - mnew);

    float ps = 0.0f;
    float pv[4][4];
    #pragma unroll
    for (int lb = 0; lb < 4; ++lb)
      #pragma unroll
      for (int r = 0; r < 4; ++r) {
        float p = __expf(sv[lb][r] - mnew);
        pv[lb][r] = p; ps += p;
      }
    ps += __shfl_xor(ps, 16);
    ps += __shfl_xor(ps, 32);
    lsum = lsum * scale + ps;
    mrun = mnew;

    // write P rows (fp16) to per-wave swizzled LDS: byte (lp*128 + 2l) ^ ((lp&7)<<4)
    {
      char* Pw = (char*)&Plds[w][0];
      #pragma unroll
      for (int lb = 0; lb < 4; ++lb) {
        H2U lo, hi;
        lo.h[0] = (_Float16)pv[lb][0]; lo.h[1] = (_Float16)pv[lb][1];
        hi.h[0] = (_Float16)pv[lb][2]; hi.h[1] = (_Float16)pv[lb][3];
        int base = lp * 128 + lb * 32 + gq * 8;   // l = 16lb + 4gq
        int swz  = (lp & 7) << 4;
        *(uint*)(Pw + ((base ^ swz)))     = lo.u;
        *(uint*)(Pw + ((base ^ swz) + 4)) = hi.u;
      }
      if (lane < 16) Slds[w * 16 + lp] = scale;
    }

    __syncthreads();   // P + scale visible to all waves

    // ---- PV: wave computes O[all 64 q][c slice 64w..64w+64) ----
    #pragma unroll
    for (int qb = 0; qb < 4; ++qb) {
      f32x4 sc = *(const f32x4*)&Slds[qb * 16 + gq * 4];
      #pragma unroll
      for (int cb = 0; cb < 4; ++cb) acc[qb][cb] *= sc;
    }

    #pragma unroll
    for (int kc = 0; kc < 2; ++kc) {
      half8 pa[4];
      #pragma unroll
      for (int qb = 0; qb < 4; ++qb) {
        const char* Pr = (const char*)&Plds[qb][0];
        int off = (lp * 128 + gq * 16 + kc * 64) ^ ((lp & 7) << 4);
        pa[qb] = *(const half8*)(Pr + off);
      }
      // PV B-frags via hardware transpose read (T10):
      // out[j] = R[kc*32 + gq*8 + u*4 + j][w*64 + cb*16 + lp]
      half4 tr[4][2];
      #pragma unroll
      for (int cb = 0; cb < 4; ++cb) {
        #pragma unroll
        for (int u = 0; u < 2; ++u) {
          asm volatile("ds_read_b64_tr_b16 %0, %1 offset:%2"
                       : "=v"(tr[cb][u])
                       : "v"(trbase), "i"(kc * 16384 + u * 2048 + cb * 128));
        }
      }
      asm volatile("s_waitcnt lgkmcnt(0)" ::: "memory");
      __builtin_amdgcn_sched_barrier(0);

      #pragma unroll
      for (int qb = 0; qb < 4; ++qb)
        #pragma unroll
        for (int cb = 0; cb < 4; ++cb) {
          half8 bv = __builtin_shufflevector(tr[cb][0], tr[cb][1], 0, 1, 2, 3, 4, 5, 6, 7);
          acc[qb][cb] = __builtin_amdgcn_mfma_f32_16x16x32_f16(pa[qb], bv, acc[qb][cb], 0, 0, 0);
        }
    }

    __syncthreads();   // frees R buffer (for stage t+2) and P region
  }

  // ---- epilogue: divide by sum-exp, write fp32 ----
  if (lane < 16) Llds[w * 16 + lp] = lsum;
  __syncthreads();

  float* ob = out + (long)bn * NQ * Cc;
  #pragma unroll
  for (int qb = 0; qb < 4; ++qb) {
    f32x4 lv = *(const f32x4*)&Llds[qb * 16 + gq * 4];
    #pragma unroll
    for (int r = 0; r < 4; ++r) {
      const float iv = 1.0f / lv[r];
      const int q = qb * 16 + gq * 4 + r;
      #pragma unroll
      for (int cb = 0; cb < 4; ++cb) {
        const int c = w * 64 + cb * 16 + lp;
        ob[q * Cc + c] = acc[qb][cb][r] * iv;
      }
    }
  }
}

extern "C" void kernel_launch(void* const* d_in, const int* in_sizes, int n_in,
                              void* d_out, int out_size, void* d_ws, size_t ws_size,
                              hipStream_t stream) {
  const float* img = (const float*)d_in[0];
  const float* qry = (const float*)d_in[1];
  float* outp      = (float*)d_out;
  dim3 grid(Bc * 49), block(256);
  attn_cells<<<grid, block, 0, stream>>>(img, qry, outp);
}